// Round 3
// baseline (248.821 us; speedup 1.0000x reference)
//
#include <hip/hip_runtime.h>
#include <math.h>

// ---------------------------------------------------------------------------
// FPSANConv2d: out = conv3x3(x, Qt(w)) + b + sigmoid(gate)*(conv3x3(x, Qt(w_child)) + b_child)
// Fused: W_eff = Qt(w) + g*Qt(w_child) (bf16), b_eff = b + g*b_child, ONE conv.
//
// Round 3:
//   k1 reduce_abs_part : 9-block deterministic f64 partial reduce (parallel)
//   k2 quant_combine   : sums partials, ternary-quantize + gate-combine -> wq[tap][oc][ci]
//   k3 transpose_x     : NCHW f32 -> padded NHWC bf16 via odd-stride LDS tile
//                        (conflict-free, coalesced both sides)
//   k4 conv_mfma       : implicit GEMM from global, XCD-band swizzle (halo rows
//                        share an XCD's L2), 8 blocks/CU, nontemporal C stores.
// ---------------------------------------------------------------------------

typedef __attribute__((ext_vector_type(8))) short short8;   // 8 bf16 (4 VGPRs)
typedef __attribute__((ext_vector_type(4))) float float4v;  // MFMA C/D frag

__device__ inline unsigned short f2bf(float f) {
  union { float f; unsigned u; } v; v.f = f;
  unsigned u = v.u;
  return (unsigned short)((u + 0x7FFFu + ((u >> 16) & 1u)) >> 16);  // RNE
}

// ---- k1: deterministic partial |w| sums: 9 blocks x 1024 x 4 elems ----
__global__ __launch_bounds__(1024) void reduce_abs_part(const float* __restrict__ w,
                                                        const float* __restrict__ wc,
                                                        double* __restrict__ part) {
  const int base = blockIdx.x * 4096 + threadIdx.x;
  double a = 0.0, c = 0.0;
#pragma unroll
  for (int i = 0; i < 4; ++i) {
    a += (double)fabsf(w[base + i * 1024]);
    c += (double)fabsf(wc[base + i * 1024]);
  }
#pragma unroll
  for (int off = 32; off > 0; off >>= 1) {
    a += __shfl_down(a, off);
    c += __shfl_down(c, off);
  }
  __shared__ double sa[16], sc[16];
  int wv = threadIdx.x >> 6;
  if ((threadIdx.x & 63) == 0) { sa[wv] = a; sc[wv] = c; }
  __syncthreads();
  if (threadIdx.x == 0) {
    double ta = 0.0, tc = 0.0;
#pragma unroll
    for (int i = 0; i < 16; ++i) { ta += sa[i]; tc += sc[i]; }
    part[blockIdx.x] = ta;
    part[9 + blockIdx.x] = tc;
  }
}

// ---- k2: ternary-quantize both weights, combine with gate, emit bf16 ----
// wq[tap][oc][ci], tap = kh*3+kw : ci-contiguous for 16B B-fragment loads.
__global__ void quant_combine(const float* __restrict__ w, const float* __restrict__ wc,
                              const float* __restrict__ b, const float* __restrict__ bc,
                              const float* __restrict__ gate, const double* __restrict__ part,
                              unsigned short* __restrict__ wq, float* __restrict__ beff) {
  double s0 = 0.0, s1 = 0.0;
#pragma unroll
  for (int i = 0; i < 9; ++i) { s0 += part[i]; s1 += part[9 + i]; }
  const float sw = fmaxf((float)(s0 * (1.0 / 36864.0)), 1e-5f);
  const float sc = fmaxf((float)(s1 * (1.0 / 36864.0)), 1e-5f);
  const float g = 1.0f / (1.0f + expf(-gate[0]));
  int idx = blockIdx.x * 256 + threadIdx.x;  // (tap, oc, ci)
  int tap = idx >> 12;
  int oc = (idx >> 6) & 63;
  int ci = idx & 63;
  int src = oc * 576 + ci * 9 + tap;  // OIHW flat
  float q1 = fminf(1.f, fmaxf(-1.f, rintf(w[src] / sw))) * sw;
  float q2 = fminf(1.f, fmaxf(-1.f, rintf(wc[src] / sc))) * sc;
  wq[idx] = f2bf(q1 + g * q2);
  if (idx < 64) beff[idx] = b[idx] + g * bc[idx];
}

// ---- k3: NCHW f32 -> zero-padded NHWC bf16  x_p[n][hp 0..129][cp 0..129][ci] ----
// Odd-stride (33 dword) LDS tile: conflict-free writes & reads, coalesced global IO.
__global__ __launch_bounds__(256) void transpose_x(const float* __restrict__ x,
                                                   unsigned short* __restrict__ xp) {
  const int bid = blockIdx.x;            // n*130 + hp
  const int n = bid / 130;
  const int hp = bid - n * 130;
  unsigned short* dst = xp + (size_t)(n * 130 + hp) * (130 * 64);
  const int tid = threadIdx.x;

  if (hp == 0 || hp == 129) {            // zero whole padded row (1040 x 16B)
    for (int j = tid; j < 1040; j += 256) ((short8*)dst)[j] = (short8)0;
    return;
  }
  const int h = hp - 1;
  __shared__ unsigned tile[128 * 33];    // [c][ci-pair], stride 33 dwords (odd)

  const float* src = x + (size_t)n * 64 * 16384 + h * 128;
  for (int k = tid; k < 4096; k += 256) {  // ci-pair major, c inner (coalesced)
    int ci2 = k >> 7;                      // 0..31
    int c = k & 127;
    unsigned lo = f2bf(src[(2 * ci2) * 16384 + c]);
    unsigned hi = f2bf(src[(2 * ci2 + 1) * 16384 + c]);
    tile[c * 33 + ci2] = lo | (hi << 16);  // bank (c+ci2)%32: 2-way, free
  }
  // zero col borders (cp=0 and cp=129)
  if (tid < 8) ((short8*)dst)[tid] = (short8)0;
  else if (tid < 16) ((short8*)dst)[1032 + (tid - 8)] = (short8)0;
  __syncthreads();
  // interior: lanes write contiguous 16B -> 1KB/wave stores
  for (int j = tid; j < 1024; j += 256) {
    int c = j >> 3;
    int q = j & 7;
    const unsigned* tp = &tile[c * 33 + q * 4];
    unsigned u0 = tp[0], u1 = tp[1], u2 = tp[2], u3 = tp[3];  // conflict-free
    short8 v;
    v[0] = (short)(u0 & 0xffff); v[1] = (short)(u0 >> 16);
    v[2] = (short)(u1 & 0xffff); v[3] = (short)(u1 >> 16);
    v[4] = (short)(u2 & 0xffff); v[5] = (short)(u2 >> 16);
    v[6] = (short)(u3 & 0xffff); v[7] = (short)(u3 >> 16);
    ((short8*)dst)[8 + j] = v;  // cp = c+1
  }
}

// ---- k4: conv as implicit GEMM, fragments straight from global (no LDS) ----
// XCD-band swizzle: XCD (bid&7) owns rows [16*xcd, 16*xcd+16) for every n, so
// halo rows h-1/h/h+1 are fetched into ONE XCD's L2. 8 blocks/CU resident.
__global__ __launch_bounds__(256, 8) void conv_mfma(
    const unsigned short* __restrict__ xp, const unsigned short* __restrict__ wq,
    const float* __restrict__ beff, float* __restrict__ out) {
  const int bid = blockIdx.x;
  const int xcd = bid & 7;
  const int s = bid >> 3;          // 0..255
  const int n = s >> 4;            // 0..15
  const int h = xcd * 16 + (s & 15);
  const int tid = threadIdx.x;
  const int lane = tid & 63;
  const int wv = tid >> 6;
  const int wbase = wv * 32;
  const int ln15 = lane & 15;
  const int koff = (lane >> 4) << 3;

  const unsigned short* xrow = xp + (size_t)(n * 130 + h) * (130 * 64);

  float4v acc[2][4] = {};

#pragma unroll
  for (int tap = 0; tap < 9; ++tap) {
    const int dh = tap / 3;
    const int dw = tap - dh * 3;
    const unsigned short* ap = xrow + (dh * 130 + wbase + dw + ln15) * 64 + koff;
    const unsigned short* wp = wq + tap * 4096 + ln15 * 64 + koff;
#pragma unroll
    for (int cc = 0; cc < 64; cc += 32) {
      short8 a0 = *(const short8*)(ap + cc);
      short8 a1 = *(const short8*)(ap + cc + 1024);   // +16 pixels
      short8 b0 = *(const short8*)(wp + cc);
      short8 b1 = *(const short8*)(wp + cc + 1024);   // +16 oc
      short8 b2 = *(const short8*)(wp + cc + 2048);
      short8 b3 = *(const short8*)(wp + cc + 3072);
      acc[0][0] = __builtin_amdgcn_mfma_f32_16x16x32_bf16(a0, b0, acc[0][0], 0, 0, 0);
      acc[1][0] = __builtin_amdgcn_mfma_f32_16x16x32_bf16(a1, b0, acc[1][0], 0, 0, 0);
      acc[0][1] = __builtin_amdgcn_mfma_f32_16x16x32_bf16(a0, b1, acc[0][1], 0, 0, 0);
      acc[1][1] = __builtin_amdgcn_mfma_f32_16x16x32_bf16(a1, b1, acc[1][1], 0, 0, 0);
      acc[0][2] = __builtin_amdgcn_mfma_f32_16x16x32_bf16(a0, b2, acc[0][2], 0, 0, 0);
      acc[1][2] = __builtin_amdgcn_mfma_f32_16x16x32_bf16(a1, b2, acc[1][2], 0, 0, 0);
      acc[0][3] = __builtin_amdgcn_mfma_f32_16x16x32_bf16(a0, b3, acc[0][3], 0, 0, 0);
      acc[1][3] = __builtin_amdgcn_mfma_f32_16x16x32_bf16(a1, b3, acc[1][3], 0, 0, 0);
    }
  }

  // epilogue: C/D layout col=lane&15 (oc), row=(lane>>4)*4+reg (pixel)
  const int rq = lane >> 4;
  float bias[4];
#pragma unroll
  for (int q = 0; q < 4; ++q) bias[q] = beff[q * 16 + ln15];
#pragma unroll
  for (int mf = 0; mf < 2; ++mf) {
#pragma unroll
    for (int q = 0; q < 4; ++q) {
      float4v v = acc[mf][q] + bias[q];
      int oc = q * 16 + ln15;
      float* op = out + (((n * 64 + oc) * 128 + h) * 128 + wbase + mf * 16 + rq * 4);
      __builtin_nontemporal_store(v, (float4v*)op);  // streaming: keep L2 for x/B
    }
  }
}

extern "C" void kernel_launch(void* const* d_in, const int* in_sizes, int n_in,
                              void* d_out, int out_size, void* d_ws, size_t ws_size,
                              hipStream_t stream) {
  const float* x = (const float*)d_in[0];
  const float* w = (const float*)d_in[1];
  const float* b = (const float*)d_in[2];
  const float* wc = (const float*)d_in[3];
  const float* bc = (const float*)d_in[4];
  const float* gate = (const float*)d_in[5];

  // ws: wq bf16[36864]=73728B | beff f32[64] @73728 | part f64[18] @73984
  //     | x_p bf16[16*130*130*64]=34611200B @74240
  unsigned short* wq = (unsigned short*)d_ws;
  float* beff = (float*)((char*)d_ws + 73728);
  double* part = (double*)((char*)d_ws + 73984);
  unsigned short* xp = (unsigned short*)((char*)d_ws + 74240);

  reduce_abs_part<<<9, 1024, 0, stream>>>(w, wc, part);
  transpose_x<<<16 * 130, 256, 0, stream>>>(x, xp);          // independent of k1
  quant_combine<<<144, 256, 0, stream>>>(w, wc, b, bc, gate, part, wq, beff);
  conv_mfma<<<2048, 256, 0, stream>>>(xp, wq, beff, (float*)d_out);
}

// Round 4
// 216.085 us; speedup vs baseline: 1.1515x; 1.1515x over previous
//
#include <hip/hip_runtime.h>
#include <math.h>

// ---------------------------------------------------------------------------
// FPSANConv2d: out = conv3x3(x, Qt(w)) + b + sigmoid(gate)*(conv3x3(x, Qt(w_child)) + b_child)
// Fused: W_eff = Qt(w) + g*Qt(w_child) (bf16), b_eff = b + g*b_child, ONE conv.
//
// Round 4:
//   k1 reduce_abs_part : 9-block deterministic f64 partial reduce
//   k2 quant_combine   : ternary-quantize + gate-combine -> wq[tap][oc][ci] bf16
//   k3 transpose_x     : NCHW f32 -> padded NHWC bf16, direct gather (no LDS)
//   k4 conv_mfma       : implicit GEMM; wave tile 64px x 64oc, block = 2 rows;
//                        2-stage tap pipeline (load t+1 under t's 32 MFMAs);
//                        no LDS, no spills (launch_bounds(256,2)), normal stores.
// ---------------------------------------------------------------------------

typedef __attribute__((ext_vector_type(8))) short short8;   // 8 bf16 (4 VGPRs)
typedef __attribute__((ext_vector_type(4))) float float4v;  // MFMA C/D frag

__device__ inline unsigned short f2bf(float f) {
  union { float f; unsigned u; } v; v.f = f;
  unsigned u = v.u;
  return (unsigned short)((u + 0x7FFFu + ((u >> 16) & 1u)) >> 16);  // RNE
}

// ---- k1: deterministic partial |w| sums: 9 blocks x 1024 x 4 elems ----
__global__ __launch_bounds__(1024) void reduce_abs_part(const float* __restrict__ w,
                                                        const float* __restrict__ wc,
                                                        double* __restrict__ part) {
  const int base = blockIdx.x * 4096 + threadIdx.x;
  double a = 0.0, c = 0.0;
#pragma unroll
  for (int i = 0; i < 4; ++i) {
    a += (double)fabsf(w[base + i * 1024]);
    c += (double)fabsf(wc[base + i * 1024]);
  }
#pragma unroll
  for (int off = 32; off > 0; off >>= 1) {
    a += __shfl_down(a, off);
    c += __shfl_down(c, off);
  }
  __shared__ double sa[16], sc[16];
  int wv = threadIdx.x >> 6;
  if ((threadIdx.x & 63) == 0) { sa[wv] = a; sc[wv] = c; }
  __syncthreads();
  if (threadIdx.x == 0) {
    double ta = 0.0, tc = 0.0;
#pragma unroll
    for (int i = 0; i < 16; ++i) { ta += sa[i]; tc += sc[i]; }
    part[blockIdx.x] = ta;
    part[9 + blockIdx.x] = tc;
  }
}

// ---- k2: ternary-quantize both weights, combine with gate, emit bf16 ----
// wq[tap][oc][ci], tap = kh*3+kw : ci-contiguous for 16B B-fragment loads.
__global__ void quant_combine(const float* __restrict__ w, const float* __restrict__ wc,
                              const float* __restrict__ b, const float* __restrict__ bc,
                              const float* __restrict__ gate, const double* __restrict__ part,
                              unsigned short* __restrict__ wq, float* __restrict__ beff) {
  double s0 = 0.0, s1 = 0.0;
#pragma unroll
  for (int i = 0; i < 9; ++i) { s0 += part[i]; s1 += part[9 + i]; }
  const float sw = fmaxf((float)(s0 * (1.0 / 36864.0)), 1e-5f);
  const float sc = fmaxf((float)(s1 * (1.0 / 36864.0)), 1e-5f);
  const float g = 1.0f / (1.0f + expf(-gate[0]));
  int idx = blockIdx.x * 256 + threadIdx.x;  // (tap, oc, ci)
  int tap = idx >> 12;
  int oc = (idx >> 6) & 63;
  int ci = idx & 63;
  int src = oc * 576 + ci * 9 + tap;  // OIHW flat
  float q1 = fminf(1.f, fmaxf(-1.f, rintf(w[src] / sw))) * sw;
  float q2 = fminf(1.f, fmaxf(-1.f, rintf(wc[src] / sc))) * sc;
  wq[idx] = f2bf(q1 + g * q2);
  if (idx < 64) beff[idx] = b[idx] + g * bc[idx];
}

// ---- k3: NCHW f32 -> zero-padded NHWC bf16  x_p[n][hp][cp][ci], no LDS ----
// One block per (n,hp). Each thread builds 16B output chunks via 8 coalesced
// plane-strided loads (MLP 8), packs to bf16, one 16B store.
__global__ __launch_bounds__(256) void transpose_x(const float* __restrict__ x,
                                                   unsigned short* __restrict__ xp) {
  const int bid = blockIdx.x;            // n*130 + hp
  const int n = bid / 130;
  const int hp = bid - n * 130;
  unsigned short* dst = xp + (size_t)(n * 130 + hp) * (130 * 64);
  const int tid = threadIdx.x;

  if (hp == 0 || hp == 129) {            // zero whole padded row (1040 x 16B)
    for (int j = tid; j < 1040; j += 256) ((short8*)dst)[j] = (short8)0;
    return;
  }
  const int h = hp - 1;
  const float* base = x + (size_t)n * 64 * 16384 + h * 128;  // + ci*16384 + c

  for (int j = tid; j < 1040; j += 256) {  // chunk = (q = ci-octet, cp)
    int q = j / 130;
    int cp = j - q * 130;
    short8 v = (short8)0;
    if (cp >= 1 && cp <= 128) {
      int c = cp - 1;
      const float* s = base + (q * 8) * 16384 + c;  // lanes: consecutive c -> coalesced
      float f0 = s[0];
      float f1 = s[16384];
      float f2 = s[2 * 16384];
      float f3 = s[3 * 16384];
      float f4 = s[4 * 16384];
      float f5 = s[5 * 16384];
      float f6 = s[6 * 16384];
      float f7 = s[7 * 16384];
      v[0] = (short)f2bf(f0); v[1] = (short)f2bf(f1);
      v[2] = (short)f2bf(f2); v[3] = (short)f2bf(f3);
      v[4] = (short)f2bf(f4); v[5] = (short)f2bf(f5);
      v[6] = (short)f2bf(f6); v[7] = (short)f2bf(f7);
    }
    ((short8*)dst)[cp * 8 + q] = v;
  }
}

// ---- k4: conv as implicit GEMM; wave = 64px x 64oc; block = 2 rows ----
// 2-stage software pipeline over the 9 taps: fragments for tap t+1 are loaded
// while tap t's 32 MFMAs execute (~155 cyc slack ~ covers an L2 hit).
__global__ __launch_bounds__(256, 2) void conv_mfma(
    const unsigned short* __restrict__ xp, const unsigned short* __restrict__ wq,
    const float* __restrict__ beff, float* __restrict__ out) {
  const int bid = blockIdx.x;        // n*64 + s
  const int n = bid >> 6;
  const int s = bid & 63;
  const int h0 = s * 2;              // output rows h0, h0+1
  const int tid = threadIdx.x;
  const int lane = tid & 63;
  const int wv = tid >> 6;
  const int rw = wv >> 1;            // which output row (0/1)
  const int pxh = (wv & 1) * 64;     // pixel half
  const int ln15 = lane & 15;
  const int koff = (lane >> 4) << 3; // 0,8,16,24

  // padded rows for output row h = h0+rw are hp = h .. h+2  (= h0+rw+dh)
  const unsigned short* xbase =
      xp + (size_t)((n * 130 + h0 + rw) * 130) * 64 + (size_t)(pxh + ln15) * 64 + koff;
  const unsigned short* wbase = wq + ln15 * 64 + koff;

  short8 A[2][2][4], B[2][2][4];
  float4v acc[4][4] = {};  // [mf][qd]

  auto load_tap = [&](int tap, short8 Ab[2][4], short8 Bb[2][4]) {
    const int dh = tap / 3;
    const int dw = tap - dh * 3;
    const unsigned short* ap = xbase + (dh * 130 + dw) * 64;
    const unsigned short* wp = wbase + tap * 4096;
#pragma unroll
    for (int cc2 = 0; cc2 < 2; ++cc2) {
      const int cc = cc2 * 32;
#pragma unroll
      for (int qd = 0; qd < 4; ++qd)
        Bb[cc2][qd] = *(const short8*)(wp + qd * 1024 + cc);
#pragma unroll
      for (int mf = 0; mf < 4; ++mf)
        Ab[cc2][mf] = *(const short8*)(ap + mf * 16 * 64 + cc);
    }
  };

  load_tap(0, A[0], B[0]);
#pragma unroll
  for (int tap = 0; tap < 9; ++tap) {
    const int cur = tap & 1, nxt = cur ^ 1;
    if (tap < 8) load_tap(tap + 1, A[nxt], B[nxt]);
#pragma unroll
    for (int cc2 = 0; cc2 < 2; ++cc2)
#pragma unroll
      for (int mf = 0; mf < 4; ++mf)
#pragma unroll
        for (int qd = 0; qd < 4; ++qd)
          acc[mf][qd] = __builtin_amdgcn_mfma_f32_16x16x32_bf16(
              A[cur][cc2][mf], B[cur][cc2][qd], acc[mf][qd], 0, 0, 0);
  }

  // epilogue: C/D layout col=lane&15 (oc), row=(lane>>4)*4+reg (pixel)
  const int rq = lane >> 4;
  float bias[4];
#pragma unroll
  for (int q = 0; q < 4; ++q) bias[q] = beff[q * 16 + ln15];
#pragma unroll
  for (int mf = 0; mf < 4; ++mf) {
#pragma unroll
    for (int qd = 0; qd < 4; ++qd) {
      float4v v = acc[mf][qd] + bias[qd];
      int oc = qd * 16 + ln15;
      float* op = out + (((n * 64 + oc) * 128 + h0 + rw) * 128 + pxh + mf * 16 + rq * 4);
      *(float4v*)op = v;
    }
  }
}

extern "C" void kernel_launch(void* const* d_in, const int* in_sizes, int n_in,
                              void* d_out, int out_size, void* d_ws, size_t ws_size,
                              hipStream_t stream) {
  const float* x = (const float*)d_in[0];
  const float* w = (const float*)d_in[1];
  const float* b = (const float*)d_in[2];
  const float* wc = (const float*)d_in[3];
  const float* bc = (const float*)d_in[4];
  const float* gate = (const float*)d_in[5];

  // ws: wq bf16[36864]=73728B | beff f32[64] @73728 | part f64[18] @73984
  //     | x_p bf16[16*130*130*64]=34611200B @74240
  unsigned short* wq = (unsigned short*)d_ws;
  float* beff = (float*)((char*)d_ws + 73728);
  double* part = (double*)((char*)d_ws + 73984);
  unsigned short* xp = (unsigned short*)((char*)d_ws + 74240);

  reduce_abs_part<<<9, 1024, 0, stream>>>(w, wc, part);
  transpose_x<<<16 * 130, 256, 0, stream>>>(x, xp);
  quant_combine<<<144, 256, 0, stream>>>(w, wc, b, bc, gate, part, wq, beff);
  conv_mfma<<<16 * 64, 256, 0, stream>>>(xp, wq, beff, (float*)d_out);
}

// Round 5
// 199.567 us; speedup vs baseline: 1.2468x; 1.0828x over previous
//
#include <hip/hip_runtime.h>
#include <math.h>

// ---------------------------------------------------------------------------
// FPSANConv2d: out = conv3x3(x, Qt(w)) + b + sigmoid(gate)*(conv3x3(x, Qt(w_child)) + b_child)
// Fused: W_eff = Qt(w) + g*Qt(w_child) (bf16), b_eff = b + g*b_child, ONE conv.
//
// Round 5:
//   k1 reduce_abs_part : 9-block deterministic f64 partial reduce
//   k2 quant_combine   : ternary-quantize + gate-combine -> wq[tap][oc][ci] bf16
//   k3 transpose_x     : NCHW f32 -> padded NHWC bf16 via odd-stride LDS tile (R3 ver)
//   k4 conv_mfma       : R4 tile (wave 64px x 64oc, 2-row block, tap pipeline)
//                        + XCD-ownership swizzle: XCD (bid&7) owns 2 whole images,
//                        so halo rows are reused within ONE per-XCD L2 (no dup).
// ---------------------------------------------------------------------------

typedef __attribute__((ext_vector_type(8))) short short8;   // 8 bf16 (4 VGPRs)
typedef __attribute__((ext_vector_type(4))) float float4v;  // MFMA C/D frag

__device__ inline unsigned short f2bf(float f) {
  union { float f; unsigned u; } v; v.f = f;
  unsigned u = v.u;
  return (unsigned short)((u + 0x7FFFu + ((u >> 16) & 1u)) >> 16);  // RNE
}

// ---- k1: deterministic partial |w| sums: 9 blocks x 1024 x 4 elems ----
__global__ __launch_bounds__(1024) void reduce_abs_part(const float* __restrict__ w,
                                                        const float* __restrict__ wc,
                                                        double* __restrict__ part) {
  const int base = blockIdx.x * 4096 + threadIdx.x;
  double a = 0.0, c = 0.0;
#pragma unroll
  for (int i = 0; i < 4; ++i) {
    a += (double)fabsf(w[base + i * 1024]);
    c += (double)fabsf(wc[base + i * 1024]);
  }
#pragma unroll
  for (int off = 32; off > 0; off >>= 1) {
    a += __shfl_down(a, off);
    c += __shfl_down(c, off);
  }
  __shared__ double sa[16], sc[16];
  int wv = threadIdx.x >> 6;
  if ((threadIdx.x & 63) == 0) { sa[wv] = a; sc[wv] = c; }
  __syncthreads();
  if (threadIdx.x == 0) {
    double ta = 0.0, tc = 0.0;
#pragma unroll
    for (int i = 0; i < 16; ++i) { ta += sa[i]; tc += sc[i]; }
    part[blockIdx.x] = ta;
    part[9 + blockIdx.x] = tc;
  }
}

// ---- k2: ternary-quantize both weights, combine with gate, emit bf16 ----
// wq[tap][oc][ci], tap = kh*3+kw : ci-contiguous for 16B B-fragment loads.
__global__ void quant_combine(const float* __restrict__ w, const float* __restrict__ wc,
                              const float* __restrict__ b, const float* __restrict__ bc,
                              const float* __restrict__ gate, const double* __restrict__ part,
                              unsigned short* __restrict__ wq, float* __restrict__ beff) {
  double s0 = 0.0, s1 = 0.0;
#pragma unroll
  for (int i = 0; i < 9; ++i) { s0 += part[i]; s1 += part[9 + i]; }
  const float sw = fmaxf((float)(s0 * (1.0 / 36864.0)), 1e-5f);
  const float sc = fmaxf((float)(s1 * (1.0 / 36864.0)), 1e-5f);
  const float g = 1.0f / (1.0f + expf(-gate[0]));
  int idx = blockIdx.x * 256 + threadIdx.x;  // (tap, oc, ci)
  int tap = idx >> 12;
  int oc = (idx >> 6) & 63;
  int ci = idx & 63;
  int src = oc * 576 + ci * 9 + tap;  // OIHW flat
  float q1 = fminf(1.f, fmaxf(-1.f, rintf(w[src] / sw))) * sw;
  float q2 = fminf(1.f, fmaxf(-1.f, rintf(wc[src] / sc))) * sc;
  wq[idx] = f2bf(q1 + g * q2);
  if (idx < 64) beff[idx] = b[idx] + g * bc[idx];
}

// ---- k3: NCHW f32 -> zero-padded NHWC bf16  x_p[n][hp 0..129][cp 0..129][ci] ----
// Odd-stride (33 dword) LDS tile: conflict-free writes & reads, coalesced global IO.
__global__ __launch_bounds__(256) void transpose_x(const float* __restrict__ x,
                                                   unsigned short* __restrict__ xp) {
  const int bid = blockIdx.x;            // n*130 + hp
  const int n = bid / 130;
  const int hp = bid - n * 130;
  unsigned short* dst = xp + (size_t)(n * 130 + hp) * (130 * 64);
  const int tid = threadIdx.x;

  if (hp == 0 || hp == 129) {            // zero whole padded row (1040 x 16B)
    for (int j = tid; j < 1040; j += 256) ((short8*)dst)[j] = (short8)0;
    return;
  }
  const int h = hp - 1;
  __shared__ unsigned tile[128 * 33];    // [c][ci-pair], stride 33 dwords (odd)

  const float* src = x + (size_t)n * 64 * 16384 + h * 128;
  for (int k = tid; k < 4096; k += 256) {  // ci-pair major, c inner (coalesced)
    int ci2 = k >> 7;                      // 0..31
    int c = k & 127;
    unsigned lo = f2bf(src[(2 * ci2) * 16384 + c]);
    unsigned hi = f2bf(src[(2 * ci2 + 1) * 16384 + c]);
    tile[c * 33 + ci2] = lo | (hi << 16);  // bank (c+ci2)%32: 2-way, free
  }
  // zero col borders (cp=0 and cp=129)
  if (tid < 8) ((short8*)dst)[tid] = (short8)0;
  else if (tid < 16) ((short8*)dst)[1032 + (tid - 8)] = (short8)0;
  __syncthreads();
  // interior: lanes write contiguous 16B -> 1KB/wave stores
  for (int j = tid; j < 1024; j += 256) {
    int c = j >> 3;
    int q = j & 7;
    const unsigned* tp = &tile[c * 33 + q * 4];
    unsigned u0 = tp[0], u1 = tp[1], u2 = tp[2], u3 = tp[3];  // conflict-free
    short8 v;
    v[0] = (short)(u0 & 0xffff); v[1] = (short)(u0 >> 16);
    v[2] = (short)(u1 & 0xffff); v[3] = (short)(u1 >> 16);
    v[4] = (short)(u2 & 0xffff); v[5] = (short)(u2 >> 16);
    v[6] = (short)(u3 & 0xffff); v[7] = (short)(u3 >> 16);
    ((short8*)dst)[8 + j] = v;  // cp = c+1
  }
}

// ---- k4: conv as implicit GEMM; wave = 64px x 64oc; block = 2 rows ----
// XCD-ownership swizzle: XCD (bid&7) processes 2 complete images, so all halo
// sharing happens inside one XCD's 4MB L2 (zero cross-XCD duplication).
// 2-stage tap pipeline: load tap t+1's fragments under tap t's 32 MFMAs.
__global__ __launch_bounds__(256, 2) void conv_mfma(
    const unsigned short* __restrict__ xp, const unsigned short* __restrict__ wq,
    const float* __restrict__ beff, float* __restrict__ out) {
  const int bid = blockIdx.x;        // 1024 blocks
  const int xcd = bid & 7;
  const int u = bid >> 3;            // 0..127
  const int n = xcd * 2 + (u >> 6);  // XCD owns images 2*xcd, 2*xcd+1
  const int h0 = (u & 63) * 2;       // output rows h0, h0+1
  const int tid = threadIdx.x;
  const int lane = tid & 63;
  const int wv = tid >> 6;
  const int rw = wv >> 1;            // which output row (0/1)
  const int pxh = (wv & 1) * 64;     // pixel half
  const int ln15 = lane & 15;
  const int koff = (lane >> 4) << 3; // 0,8,16,24

  const unsigned short* xbase =
      xp + (size_t)((n * 130 + h0 + rw) * 130) * 64 + (size_t)(pxh + ln15) * 64 + koff;
  const unsigned short* wbase = wq + ln15 * 64 + koff;

  short8 A[2][2][4], B[2][2][4];
  float4v acc[4][4] = {};  // [mf][qd]

  auto load_tap = [&](int tap, short8 Ab[2][4], short8 Bb[2][4]) {
    const int dh = tap / 3;
    const int dw = tap - dh * 3;
    const unsigned short* ap = xbase + (dh * 130 + dw) * 64;
    const unsigned short* wp = wbase + tap * 4096;
#pragma unroll
    for (int cc2 = 0; cc2 < 2; ++cc2) {
      const int cc = cc2 * 32;
#pragma unroll
      for (int qd = 0; qd < 4; ++qd)
        Bb[cc2][qd] = *(const short8*)(wp + qd * 1024 + cc);
#pragma unroll
      for (int mf = 0; mf < 4; ++mf)
        Ab[cc2][mf] = *(const short8*)(ap + mf * 16 * 64 + cc);
    }
  };

  load_tap(0, A[0], B[0]);
#pragma unroll
  for (int tap = 0; tap < 9; ++tap) {
    const int cur = tap & 1, nxt = cur ^ 1;
    if (tap < 8) load_tap(tap + 1, A[nxt], B[nxt]);
#pragma unroll
    for (int cc2 = 0; cc2 < 2; ++cc2)
#pragma unroll
      for (int mf = 0; mf < 4; ++mf)
#pragma unroll
        for (int qd = 0; qd < 4; ++qd)
          acc[mf][qd] = __builtin_amdgcn_mfma_f32_16x16x32_bf16(
              A[cur][cc2][mf], B[cur][cc2][qd], acc[mf][qd], 0, 0, 0);
  }

  // epilogue: C/D layout col=lane&15 (oc), row=(lane>>4)*4+reg (pixel)
  const int rq = lane >> 4;
  float bias[4];
#pragma unroll
  for (int q = 0; q < 4; ++q) bias[q] = beff[q * 16 + ln15];
#pragma unroll
  for (int mf = 0; mf < 4; ++mf) {
#pragma unroll
    for (int qd = 0; qd < 4; ++qd) {
      float4v v = acc[mf][qd] + bias[qd];
      int oc = qd * 16 + ln15;
      float* op = out + (((n * 64 + oc) * 128 + h0 + rw) * 128 + pxh + mf * 16 + rq * 4);
      *(float4v*)op = v;
    }
  }
}

extern "C" void kernel_launch(void* const* d_in, const int* in_sizes, int n_in,
                              void* d_out, int out_size, void* d_ws, size_t ws_size,
                              hipStream_t stream) {
  const float* x = (const float*)d_in[0];
  const float* w = (const float*)d_in[1];
  const float* b = (const float*)d_in[2];
  const float* wc = (const float*)d_in[3];
  const float* bc = (const float*)d_in[4];
  const float* gate = (const float*)d_in[5];

  // ws: wq bf16[36864]=73728B | beff f32[64] @73728 | part f64[18] @73984
  //     | x_p bf16[16*130*130*64]=34611200B @74240
  unsigned short* wq = (unsigned short*)d_ws;
  float* beff = (float*)((char*)d_ws + 73728);
  double* part = (double*)((char*)d_ws + 73984);
  unsigned short* xp = (unsigned short*)((char*)d_ws + 74240);

  transpose_x<<<16 * 130, 256, 0, stream>>>(x, xp);
  reduce_abs_part<<<9, 1024, 0, stream>>>(w, wc, part);
  quant_combine<<<144, 256, 0, stream>>>(w, wc, b, bc, gate, part, wq, beff);
  conv_mfma<<<16 * 64, 256, 0, stream>>>(xp, wq, beff, (float*)d_out);
}